// Round 2
// baseline (384.795 us; speedup 1.0000x reference)
//
#include <hip/hip_runtime.h>
#include <math.h>

// Problem constants
#define NB 128
#define NR 512
#define NC 81
#define NDK 64
#define NRK 10
#define NROWS (NB * NR)  // 65536

#define LOG2E 1.44269504088896340736f

// ---------------------------------------------------------------------------
// Kernel A: per-row q/k projection + label (argmax) + xmax (row max).
// Block: 128 threads (2 waves). threads 0..63 compute q (d=t), 64..127 k.
// Each thread keeps its W column (81 f32) in registers, reused for 32 rows.
// x rows staged in LDS (padded to 84, zeros in tail), read as uniform float4.
// ---------------------------------------------------------------------------
#define KA_ROWS 32
#define KA_THREADS 128

__global__ __launch_bounds__(KA_THREADS) void qk_label_kernel(
    const float* __restrict__ x,
    const float* __restrict__ Wq, const float* __restrict__ bq,
    const float* __restrict__ Wk, const float* __restrict__ bk,
    float* __restrict__ Q, float* __restrict__ K,
    int* __restrict__ label, float* __restrict__ xmax)
{
    __shared__ float xl[KA_ROWS][84];

    const int t = threadIdx.x;
    const int d = t & 63;
    const bool isK = t >= 64;
    const float* W = isK ? Wk : Wq;
    const float bias = (isK ? bk : bq)[d];

    float w[84];
#pragma unroll
    for (int c = 0; c < 81; ++c) w[c] = W[c * 64 + d];
    w[81] = 0.f; w[82] = 0.f; w[83] = 0.f;

    const int r0 = blockIdx.x * KA_ROWS;

    // stage x rows (zero the pad)
    for (int e = t; e < KA_ROWS * 84; e += KA_THREADS) {
        int r = e / 84;
        int c = e - r * 84;
        xl[r][c] = (c < 81) ? x[(size_t)(r0 + r) * NC + c] : 0.f;
    }
    __syncthreads();

    // labels / row max (first occurrence on ties, like jnp.argmax)
    if (t < KA_ROWS) {
        float bv = -INFINITY; int bi = 0;
#pragma unroll
        for (int c = 0; c < 81; ++c) {
            float v = xl[t][c];
            if (v > bv) { bv = v; bi = c; }
        }
        label[r0 + t] = bi;
        xmax[r0 + t] = bv;
    }

    float* OUT = isK ? K : Q;
    for (int r = 0; r < KA_ROWS; ++r) {
        const float4* xr = reinterpret_cast<const float4*>(&xl[r][0]);
        float a0 = 0.f, a1 = 0.f, a2 = 0.f, a3 = 0.f;
#pragma unroll
        for (int c4 = 0; c4 < 21; ++c4) {
            float4 xv = xr[c4];
            a0 = fmaf(xv.x, w[c4 * 4 + 0], a0);
            a1 = fmaf(xv.y, w[c4 * 4 + 1], a1);
            a2 = fmaf(xv.z, w[c4 * 4 + 2], a2);
            a3 = fmaf(xv.w, w[c4 * 4 + 3], a3);
        }
        OUT[(size_t)(r0 + r) * NDK + d] = (a0 + a1) + (a2 + a3) + bias;
    }
}

// ---------------------------------------------------------------------------
// Kernel B: per-row attention scores + online softmax + top-10 + sparse FC.
// Grid: 256 blocks (128 batches x 2 halves). Block: 256 threads = 4 waves.
// Each wave owns 64 rows (lane <-> row), q row held in 64 VGPRs.
// K staged per 64-j chunk in LDS, read wave-uniform (broadcast).
// ---------------------------------------------------------------------------
__global__ __launch_bounds__(256) void attn_kernel(
    const float* __restrict__ Q, const float* __restrict__ K,
    const int* __restrict__ label, const float* __restrict__ xmax,
    const float* __restrict__ Wfc, const float* __restrict__ bfc,
    const float* __restrict__ prior, float* __restrict__ out)
{
    __shared__ float WfcS[NC * NC];    // 6561
    __shared__ float priorS[NC * NC];  // 6561
    __shared__ float bfcS[NC];
    __shared__ int   labS[NR];
    __shared__ float xmS[NR];
    __shared__ float Kl[64 * 64];

    const int t = threadIdx.x;
    const int b = blockIdx.x >> 1;
    const int half = blockIdx.x & 1;
    const int lane = t & 63;
    const int wv = t >> 6;
    const int r = half * 256 + wv * 64 + lane;  // row within batch
    const int g = b * NR + r;                   // global row

    for (int e = t; e < NC * NC; e += 256) { WfcS[e] = Wfc[e]; priorS[e] = prior[e]; }
    if (t < NC) bfcS[t] = bfc[t];
    for (int e = t; e < NR; e += 256) { labS[e] = label[b * NR + e]; xmS[e] = xmax[b * NR + e]; }

    // load q row into registers
    float q[64];
    const float4* qg = reinterpret_cast<const float4*>(&Q[(size_t)g * NDK]);
#pragma unroll
    for (int i = 0; i < 16; ++i) {
        float4 v = qg[i];
        q[4 * i + 0] = v.x; q[4 * i + 1] = v.y; q[4 * i + 2] = v.z; q[4 * i + 3] = v.w;
    }

    float m = -INFINITY, lsum = 0.f;
    float tv[10]; int ti[10];
#pragma unroll
    for (int i = 0; i < 10; ++i) { tv[i] = -INFINITY; ti[i] = 0; }

    __syncthreads();
    const int li = labS[r];

    for (int jc = 0; jc < NR; jc += 64) {
        __syncthreads();  // protect Kl from previous chunk's readers
        // stage K chunk: 64 rows x 64 f32 = 4096 floats, fully coalesced
        const float4* kg = reinterpret_cast<const float4*>(&K[(size_t)(b * NR + jc) * NDK]);
        float4* kls = reinterpret_cast<float4*>(Kl);
#pragma unroll
        for (int s = 0; s < 4; ++s) kls[t + 256 * s] = kg[t + 256 * s];
        __syncthreads();

#pragma unroll 4
        for (int jj = 0; jj < 64; ++jj) {
            const float4* kj = reinterpret_cast<const float4*>(&Kl[jj * 64]);
            float s0 = 0.f, s1 = 0.f, s2 = 0.f, s3 = 0.f;
#pragma unroll
            for (int d4 = 0; d4 < 16; ++d4) {
                float4 kv = kj[d4];
                s0 = fmaf(q[4 * d4 + 0], kv.x, s0);
                s1 = fmaf(q[4 * d4 + 1], kv.y, s1);
                s2 = fmaf(q[4 * d4 + 2], kv.z, s2);
                s3 = fmaf(q[4 * d4 + 3], kv.w, s3);
            }
            float sc = ((s0 + s1) + (s2 + s3)) * 0.125f;  // 1/sqrt(64)

            // online softmax (exp2 domain)
            float mn = fmaxf(m, sc);
            lsum = lsum * exp2f((m - mn) * LOG2E) + exp2f((sc - mn) * LOG2E);
            m = mn;

            // top-10 sorted insert; strict > reproduces jax top_k's
            // (value desc, index asc) tie-break since j increases.
            if (sc > tv[9]) {
                const int j = jc + jj;
#pragma unroll
                for (int i = 9; i >= 1; --i) {
                    bool sh = sc > tv[i - 1];
                    float nv = sh ? tv[i - 1] : sc;
                    int   ni = sh ? ti[i - 1] : j;
                    if (sc > tv[i]) { tv[i] = nv; ti[i] = ni; }
                }
                if (sc > tv[0]) { tv[0] = sc; ti[0] = j; }
            }
        }
    }

    // epilogue: att values, contributions, dedup-merge, relu, sparse FC
    const float inv = 1.f / lsum;
    float cv[10]; int lj[10];
#pragma unroll
    for (int k2 = 0; k2 < 10; ++k2) {
        int j = ti[k2];
        int l = labS[j];
        float val = exp2f((tv[k2] - m) * LOG2E) * inv;
        cv[k2] = (l != li) ? priorS[l * NC + li] * val * xmS[j] : 0.f;
        lj[k2] = l;
    }
    // merge duplicate labels into first occurrence (relu(0)=0 keeps dead slots inert)
#pragma unroll
    for (int a2 = 1; a2 < 10; ++a2) {
#pragma unroll
        for (int b2 = 0; b2 < a2; ++b2) {
            if (lj[a2] == lj[b2]) { cv[b2] += cv[a2]; cv[a2] = 0.f; break; }
        }
    }
#pragma unroll
    for (int k2 = 0; k2 < 10; ++k2) cv[k2] = fmaxf(cv[k2], 0.f);

    float* og = &out[(size_t)g * NC];
    for (int c = 0; c < NC; ++c) {
        float z = bfcS[c];
#pragma unroll
        for (int k2 = 0; k2 < 10; ++k2) z = fmaf(cv[k2], WfcS[lj[k2] * NC + c], z);
        og[c] = 1.f / (1.f + exp2f(-z * LOG2E));
    }
}

// ---------------------------------------------------------------------------
extern "C" void kernel_launch(void* const* d_in, const int* in_sizes, int n_in,
                              void* d_out, int out_size, void* d_ws, size_t ws_size,
                              hipStream_t stream)
{
    const float* x     = (const float*)d_in[0];
    const float* Wq    = (const float*)d_in[1];
    const float* bq    = (const float*)d_in[2];
    const float* Wk    = (const float*)d_in[3];
    const float* bk    = (const float*)d_in[4];
    const float* Wfc   = (const float*)d_in[5];
    const float* bfc   = (const float*)d_in[6];
    const float* prior = (const float*)d_in[7];
    float* out = (float*)d_out;

    // workspace layout
    float* Q     = (float*)d_ws;
    float* K     = Q + (size_t)NROWS * NDK;
    int*   label = (int*)(K + (size_t)NROWS * NDK);
    float* xmax  = (float*)(label + NROWS);

    qk_label_kernel<<<NROWS / KA_ROWS, KA_THREADS, 0, stream>>>(
        x, Wq, bq, Wk, bk, Q, K, label, xmax);

    attn_kernel<<<NB * 2, 256, 0, stream>>>(
        Q, K, label, xmax, Wfc, bfc, prior, out);
}